// Round 7
// baseline (120.118 us; speedup 1.0000x reference)
//
#include <hip/hip_runtime.h>
#include <hip/hip_bf16.h>

typedef __bf16 bf16;
typedef bf16 bf16x4 __attribute__((ext_vector_type(4)));
typedef bf16 bf16x8 __attribute__((ext_vector_type(8)));
typedef float f32x4 __attribute__((ext_vector_type(4)));

#define GLOAD16(g, l) __builtin_amdgcn_global_load_lds( \
    (const __attribute__((address_space(1))) void*)(g),  \
    (__attribute__((address_space(3))) void*)(l), 16, 0, 0)

#define EXP2F(x) __builtin_amdgcn_exp2f(x)
#define MFMA16(a, b, c) __builtin_amdgcn_mfma_f32_16x16x32_bf16(a, b, c, 0, 0, 0)

// ---------------- cast fp32 -> bf16, 8 elems/thread ----------------
__global__ __launch_bounds__(256) void cast_f32_bf16(const float* __restrict__ in,
                                                     bf16* __restrict__ out, int n8) {
  int i = blockIdx.x * 256 + threadIdx.x;
  if (i >= n8) return;
  const float4* p = (const float4*)in + (size_t)i * 2;
  float4 a = p[0], b = p[1];
  bf16x8 o;
  o[0] = (bf16)a.x; o[1] = (bf16)a.y; o[2] = (bf16)a.z; o[3] = (bf16)a.w;
  o[4] = (bf16)b.x; o[5] = (bf16)b.y; o[6] = (bf16)b.z; o[7] = (bf16)b.w;
  ((bf16x8*)out)[i] = o;
}

// ------------- transpose+cast: src[K][N] f32 -> dst[N][K] bf16 -------------
__global__ __launch_bounds__(256) void transpose_cast(const float* __restrict__ src,
                                                      bf16* __restrict__ dst,
                                                      int K, int N) {
  __shared__ float tile[32][33];
  int n0 = blockIdx.x * 32, k0 = blockIdx.y * 32;
  int tx = threadIdx.x, ty = threadIdx.y;  // 32 x 8
#pragma unroll
  for (int i = 0; i < 4; i++)
    tile[ty + 8 * i][tx] = src[(size_t)(k0 + ty + 8 * i) * N + n0 + tx];
  __syncthreads();
#pragma unroll
  for (int i = 0; i < 4; i++)
    dst[(size_t)(n0 + ty + 8 * i) * K + k0 + tx] = (bf16)tile[tx][ty + 8 * i];
}

// ---- GEMM mainloop BK=64: C[128,128] += A[.,K] * Bt[.,K]^T ----
__device__ __forceinline__ void gemm_mainloop64(const bf16* __restrict__ A,
                                                const bf16* __restrict__ Bt,
                                                int K, int m0, int n0,
                                                f32x4 acc[4][4],
                                                bf16* As, bf16* Bs) {
  int tid = threadIdx.x;
  int lane = tid & 63;
  int wave = tid >> 6;
  int wr = wave >> 1, wc = wave & 1;
  int c16 = lane & 15, g = lane >> 4;
  f32x4 z = {0.f, 0.f, 0.f, 0.f};
#pragma unroll
  for (int m = 0; m < 4; m++)
#pragma unroll
    for (int n = 0; n < 4; n++) acc[m][n] = z;
  for (int k0 = 0; k0 < K; k0 += 64) {
#pragma unroll
    for (int i = 0; i < 4; i++) {
      int cc = tid + i * 256;          // 0..1023 chunks of 16B
      int r = cc >> 3, ch = cc & 7;
      int sc = ch ^ (r & 7);
      GLOAD16(A + (size_t)(m0 + r) * K + k0 + sc * 8, As + cc * 8);
    }
#pragma unroll
    for (int i = 0; i < 4; i++) {
      int cc = tid + i * 256;
      int r = cc >> 3, ch = cc & 7;
      int sc = ch ^ (r & 7);
      GLOAD16(Bt + (size_t)(n0 + r) * K + k0 + sc * 8, Bs + cc * 8);
    }
    __syncthreads();
#pragma unroll
    for (int h = 0; h < 2; h++) {
      bf16x8 af[4], bfr[4];
#pragma unroll
      for (int m = 0; m < 4; m++) {
        int ar = wr * 64 + m * 16 + c16;
        af[m] = *(const bf16x8*)((const char*)As + ar * 128 + (((h * 4 + g) ^ (ar & 7)) << 4));
      }
#pragma unroll
      for (int n = 0; n < 4; n++) {
        int br = wc * 64 + n * 16 + c16;
        bfr[n] = *(const bf16x8*)((const char*)Bs + br * 128 + (((h * 4 + g) ^ (br & 7)) << 4));
      }
      __builtin_amdgcn_s_setprio(1);
#pragma unroll
      for (int m = 0; m < 4; m++)
#pragma unroll
        for (int n = 0; n < 4; n++)
          acc[m][n] = MFMA16(af[m], bfr[n], acc[m][n]);
      __builtin_amdgcn_s_setprio(0);
    }
    __syncthreads();
  }
}

// ---- QKV GEMM: x[4096,1024] @ WqkvT[3072,1024]^T -> q,k scaled / vT ----
__global__ __launch_bounds__(256) void gemm_qkv(const bf16* __restrict__ A,
                                                const bf16* __restrict__ Bt,
                                                bf16* __restrict__ q,
                                                bf16* __restrict__ kk,
                                                bf16* __restrict__ vt) {
  __shared__ bf16 As[128 * 64];
  __shared__ bf16 Bs[128 * 64];
  int id = blockIdx.x;
  int xc = id & 7, k = id >> 3;            // k in [0,96)
  int bn = xc * 3 + (k % 3), bm = k / 3;   // bijective: bn [0,24), bm [0,32)
  int m0 = bm * 128, n0 = bn * 128;
  f32x4 acc[4][4];
  gemm_mainloop64(A, Bt, 1024, m0, n0, acc, As, Bs);
  int lane = threadIdx.x & 63;
  int wave = threadIdx.x >> 6;
  int wr = wave >> 1, wc = wave & 1;
  int c16 = lane & 15, g = lane >> 4;
  int which = n0 >> 10;
  const float QSCALE = 0.125f * 1.4426950408889634f;
  if (which == 2) {
#pragma unroll
    for (int m = 0; m < 4; m++)
#pragma unroll
      for (int n = 0; n < 4; n++) {
        int gm0 = m0 + wr * 64 + m * 16 + g * 4;
        int gn = n0 + wc * 64 + n * 16 + c16;
        int rem = gn & 1023, h = rem >> 6, d = rem & 63;
        int b = gm0 >> 11, t0 = gm0 & 2047;
        size_t bh = (size_t)(b * 16 + h);
        bf16x4 pv;
        pv[0] = (bf16)acc[m][n][0]; pv[1] = (bf16)acc[m][n][1];
        pv[2] = (bf16)acc[m][n][2]; pv[3] = (bf16)acc[m][n][3];
        *(bf16x4*)(vt + (bh * 64 + d) * 2048 + t0) = pv;
      }
  } else {
#pragma unroll
    for (int m = 0; m < 4; m++)
#pragma unroll
      for (int n = 0; n < 4; n++)
#pragma unroll
        for (int j = 0; j < 4; j++) {
          int gm = m0 + wr * 64 + m * 16 + g * 4 + j;
          int gn = n0 + wc * 64 + n * 16 + c16;
          int rem = gn & 1023, h = rem >> 6, d = rem & 63;
          int b = gm >> 11, t = gm & 2047;
          float v = acc[m][n][j];
          size_t bh = (size_t)(b * 16 + h);
          if (which == 0) q[(bh * 2048 + t) * 64 + d]  = (bf16)(v * QSCALE);
          else            kk[(bh * 2048 + t) * 64 + d] = (bf16)v;
        }
  }
}

// ---- final GEMM: attn[4096,1024] @ WoutT[1024,1024]^T -> out fp32 ----
__global__ __launch_bounds__(256) void gemm_out(const bf16* __restrict__ A,
                                                const bf16* __restrict__ Bt,
                                                float* __restrict__ C) {
  __shared__ bf16 As[128 * 64];
  __shared__ bf16 Bs[128 * 64];
  int id = blockIdx.x;
  int bn = id & 7, bm = id >> 3;
  int m0 = bm * 128, n0 = bn * 128;
  f32x4 acc[4][4];
  gemm_mainloop64(A, Bt, 1024, m0, n0, acc, As, Bs);
  int lane = threadIdx.x & 63;
  int wave = threadIdx.x >> 6;
  int wr = wave >> 1, wc = wave & 1;
#pragma unroll
  for (int m = 0; m < 4; m++)
#pragma unroll
    for (int n = 0; n < 4; n++)
#pragma unroll
      for (int j = 0; j < 4; j++) {
        int gm = m0 + wr * 64 + m * 16 + (lane >> 4) * 4 + j;
        int gn = n0 + wc * 64 + n * 16 + (lane & 15);
        C[(size_t)gm * 1024 + gn] = acc[m][n][j];
      }
}

// ---------------- flash attention v7 (QBLK=64, 4 blocks/CU) ----------------
// 1024 blocks x 256 threads (4 waves); wave w owns q rows [qx*64+16w, +16).
// Same per-wave math as v6; 4 independent barrier domains per CU hide each
// other's staging/barrier stalls. Swizzled LDS offsets hoisted out of loop.
__global__ __launch_bounds__(256) void attn(const bf16* __restrict__ q,
                                            const bf16* __restrict__ kk,
                                            const bf16* __restrict__ vt,
                                            bf16* __restrict__ out) {
  __shared__ bf16 Ks[2][64 * 64];   // 16 KB (chunk-XOR swizzled)
  __shared__ bf16 Vs[2][64 * 64];   // 16 KB (chunk-XOR swizzled)
  __shared__ bf16 PQ[64 * 64];      // 8 KB: Q staging (prologue) / P tiles
  int tid = threadIdx.x, lane = tid & 63, w = tid >> 6;
  int c16 = lane & 15, g = (lane >> 4) & 3, g4 = g * 4;

  // ---- XCD-aware decode (bijection on 1024 blocks) ----
  // id -> XCD c (4 bh, K/V 2MB L2-resident), bhi, qq; qx via a complementary
  // map: stride-8 qq sets {a,a+8,a+16,a+24} -> qx sets with constant
  // total step count 66 (load balance across co-resident blocks).
  int id = blockIdx.x;
  int c = id & 7;
  int k = id >> 3;          // 0..127
  int bhi = k & 3;
  int qq = k >> 2;          // 0..31
  int a = qq & 7, b2 = qq >> 3;
  int qx;
  if (b2 == 0)      qx = 2 * a;
  else if (b2 == 1) qx = 31 - 2 * a;
  else if (b2 == 2) qx = 2 * a + 1;
  else              qx = 30 - 2 * a;
  int bh = 4 * c + bhi;
  int q0 = qx * 64;
  int nt = qx + 1;

  const bf16* qb = q  + (size_t)bh * 2048 * 64;
  const bf16* kb = kk + (size_t)bh * 2048 * 64;
  const bf16* vb = vt + (size_t)bh * 64 * 2048;

  // ---- prologue: stage Q[64][64] + K/V tile 0 ----
#pragma unroll
  for (int i = 0; i < 2; i++) {
    int cc = tid + i * 256;            // 0..511
    int r = cc >> 3, ds = (cc & 7) * 8;
    GLOAD16(qb + (size_t)(q0 + r) * 64 + ds, PQ + cc * 8);
  }
#pragma unroll
  for (int i = 0; i < 2; i++) {
    int cc = tid + i * 256;
    int r = cc >> 3, p = cc & 7;
    GLOAD16(kb + (size_t)r * 64 + ((p ^ (r & 7)) * 8), Ks[0] + cc * 8);
    GLOAD16(vb + (size_t)r * 2048 + ((p ^ (r & 7)) * 8), Vs[0] + cc * 8);
  }
  __syncthreads();
  bf16x8 qf[2];
#pragma unroll
  for (int ks = 0; ks < 2; ks++)
    qf[ks] = *(const bf16x8*)(PQ + (w * 16 + c16) * 64 + ks * 32 + g * 8);
  __syncthreads();   // all waves done reading Q (PQ becomes P storage)

  // ---- hoisted swizzled LDS byte offsets (loop-invariant) ----
  int koff[2][4];    // K/V fragment reads (same formula for both)
#pragma unroll
  for (int ks = 0; ks < 2; ks++)
#pragma unroll
    for (int n = 0; n < 4; n++) {
      int srow = n * 16 + c16;
      koff[ks][n] = srow * 128 + (((ks * 4 + g) ^ (srow & 7)) << 4);
    }
  int pwoff[4];      // P writes
#pragma unroll
  for (int n = 0; n < 4; n++)
    pwoff[n] = (c16 * 64 + (((2 * n + (g >> 1)) ^ (c16 & 7)) * 8) + (g & 1) * 4) * 2;
  int proff[2];      // P reads
#pragma unroll
  for (int ks = 0; ks < 2; ks++)
    proff[ks] = (c16 * 64 + (((ks * 4 + g) ^ (c16 & 7)) * 8)) * 2;

  f32x4 o[4];
  float mrun = -__builtin_inff(), lrun = 0.f;
  {
    f32x4 z = {0.f, 0.f, 0.f, 0.f};
#pragma unroll
    for (int n = 0; n < 4; n++) o[n] = z;
  }
  int qlo = q0 + w * 16;
  int qr = qlo + c16;
  char* Pb = (char*)PQ + w * 2048;   // 16x64 per-wave P tile

  for (int t = 0; t < nt; ++t) {
    int s0 = t * 64;
    int cb = t & 1;
    if (t + 1 < nt) {              // prefetch t+1 (issued before compute)
      int sn = s0 + 64;
#pragma unroll
      for (int i = 0; i < 2; i++) {
        int cc = tid + i * 256;
        int r = cc >> 3, p = cc & 7;
        GLOAD16(kb + (size_t)(sn + r) * 64 + ((p ^ (r & 7)) * 8), Ks[cb ^ 1] + cc * 8);
        GLOAD16(vb + (size_t)r * 2048 + sn + ((p ^ (r & 7)) * 8), Vs[cb ^ 1] + cc * 8);
      }
    }
    const char* Kb = (const char*)Ks + cb * 8192;
    const char* Vb = (const char*)Vs + cb * 8192;
    if (s0 <= qlo + 15) {   // wave-uniform causal skip
      // ---- QK^T: S^T = mfma(K, Q); lane holds S[q=c16][s=n*16+g4+r] ----
      f32x4 S[4];
      {
        f32x4 z = {0.f, 0.f, 0.f, 0.f};
#pragma unroll
        for (int n = 0; n < 4; n++) S[n] = z;
      }
      __builtin_amdgcn_s_setprio(1);
#pragma unroll
      for (int ks = 0; ks < 2; ks++) {
        bf16x8 kf[4];
#pragma unroll
        for (int n = 0; n < 4; n++)
          kf[n] = *(const bf16x8*)(Kb + koff[ks][n]);
#pragma unroll
        for (int n = 0; n < 4; n++)
          S[n] = MFMA16(kf[n], qf[ks], S[n]);
      }
      __builtin_amdgcn_s_setprio(0);
      // ---- causal mask (diag tiles only) ----
      if (s0 + 63 > qlo) {
#pragma unroll
        for (int n = 0; n < 4; n++)
#pragma unroll
          for (int r = 0; r < 4; r++)
            if (s0 + n * 16 + g4 + r > qr) S[n][r] = -__builtin_inff();
      }
      // ---- online softmax (exp2 domain), defer-max ----
      float tm = fmaxf(fmaxf(fmaxf(S[0][0], S[0][1]), fmaxf(S[0][2], S[0][3])),
                       fmaxf(fmaxf(S[1][0], S[1][1]), fmaxf(S[1][2], S[1][3])));
      tm = fmaxf(tm, fmaxf(fmaxf(fmaxf(S[2][0], S[2][1]), fmaxf(S[2][2], S[2][3])),
                           fmaxf(fmaxf(S[3][0], S[3][1]), fmaxf(S[3][2], S[3][3]))));
      tm = fmaxf(tm, __shfl_xor(tm, 16));
      tm = fmaxf(tm, __shfl_xor(tm, 32));
      if (!__all(tm <= mrun + 8.f)) {   // rescale (rare after first tile)
        float mnew = fmaxf(mrun, tm);
        float corr = EXP2F(mrun - mnew);
        lrun *= corr;
        mrun = mnew;
#pragma unroll
        for (int j = 0; j < 4; j++) {
          float cj = __shfl(corr, (lane & 48) | (g4 + j));
#pragma unroll
          for (int n = 0; n < 4; n++) o[n][j] *= cj;
        }
      }
      float p[4][4];
      float rs = 0.f;
#pragma unroll
      for (int n = 0; n < 4; n++)
#pragma unroll
        for (int r = 0; r < 4; r++) {
          p[n][r] = EXP2F(S[n][r] - mrun);
          rs += p[n][r];
        }
      rs += __shfl_xor(rs, 16);
      rs += __shfl_xor(rs, 32);
      lrun += rs;
      // ---- pack P to LDS ----
#pragma unroll
      for (int n = 0; n < 4; n++) {
        bf16x4 pw;
        pw[0] = (bf16)p[n][0]; pw[1] = (bf16)p[n][1];
        pw[2] = (bf16)p[n][2]; pw[3] = (bf16)p[n][3];
        *(bf16x4*)(Pb + pwoff[n]) = pw;
      }
      // ---- PV: o[q][d] += P[q][s] V^T[d][s]^T ----
      __builtin_amdgcn_s_setprio(1);
#pragma unroll
      for (int ks = 0; ks < 2; ks++) {
        bf16x8 vf[4];
#pragma unroll
        for (int n = 0; n < 4; n++)
          vf[n] = *(const bf16x8*)(Vb + koff[ks][n]);
        bf16x8 pf = *(const bf16x8*)(Pb + proff[ks]);
#pragma unroll
        for (int n = 0; n < 4; n++)
          o[n] = MFMA16(pf, vf[n], o[n]);
      }
      __builtin_amdgcn_s_setprio(0);
    }
    if (t + 1 < nt) {
      asm volatile("s_waitcnt vmcnt(0)" ::: "memory");  // t+1 staged
      __builtin_amdgcn_s_barrier();
      __builtin_amdgcn_sched_barrier(0);
    }
  }
  // ---- epilogue: o row q = qlo+g4+j, col d = n*16+c16 ----
  int b = bh >> 4, h = bh & 15;
#pragma unroll
  for (int j = 0; j < 4; j++) {
    float lv = __shfl(lrun, (lane & 48) | (g4 + j));
    float inv = 1.f / lv;
    int t = qlo + g4 + j;
#pragma unroll
    for (int n = 0; n < 4; n++) {
      int col = h * 64 + n * 16 + c16;
      out[((size_t)(b * 2048 + t)) * 1024 + col] = (bf16)(o[n][j] * inv);
    }
  }
}

extern "C" void kernel_launch(void* const* d_in, const int* in_sizes, int n_in,
                              void* d_out, int out_size, void* d_ws, size_t ws_size,
                              hipStream_t stream) {
  const float* x    = (const float*)d_in[0];
  const float* Wqkv = (const float*)d_in[1];
  const float* Wout = (const float*)d_in[2];
  float* outp = (float*)d_out;
  char* ws = (char*)d_ws;
  const size_t MB = 1024 * 1024;
  bf16* xb    = (bf16*)(ws);             // 8 MB [4096][1024]; later reused as attn out
  bf16* wqkvT = (bf16*)(ws + 8 * MB);    // 6 MB [3072][1024]
  bf16* woutT = (bf16*)(ws + 14 * MB);   // 2 MB [1024][1024]
  bf16* qb    = (bf16*)(ws + 16 * MB);   // 8 MB [32][2048][64] (scaled 0.125*log2e)
  bf16* kb    = (bf16*)(ws + 24 * MB);   // 8 MB [32][2048][64]
  bf16* vtb   = (bf16*)(ws + 32 * MB);   // 8 MB [32][64][2048]

  hipLaunchKernelGGL(cast_f32_bf16, dim3(2048), dim3(256), 0, stream,
                     x, xb, 4096 * 1024 / 8);
  hipLaunchKernelGGL(transpose_cast, dim3(96, 32), dim3(32, 8), 0, stream,
                     Wqkv, wqkvT, 1024, 3072);
  hipLaunchKernelGGL(transpose_cast, dim3(32, 32), dim3(32, 8), 0, stream,
                     Wout, woutT, 1024, 1024);
  hipLaunchKernelGGL(gemm_qkv, dim3(768), dim3(256), 0, stream,
                     xb, wqkvT, qb, kb, vtb);
  hipLaunchKernelGGL(attn, dim3(1024), dim3(256), 0, stream,
                     qb, kb, vtb, xb);
  hipLaunchKernelGGL(gemm_out, dim3(256), dim3(256), 0, stream,
                     xb, woutT, outp);
}